// Round 2
// baseline (1917.748 us; speedup 1.0000x reference)
//
#include <hip/hip_runtime.h>
#include <cstdint>

typedef _Float16 half8 __attribute__((ext_vector_type(8)));
typedef _Float16 half4v __attribute__((ext_vector_type(4)));
typedef float f32x4 __attribute__((ext_vector_type(4)));

__device__ __forceinline__ void async_copy16(const void* g, void* l) {
    __builtin_amdgcn_global_load_lds((const __attribute__((address_space(1))) void*)g,
                                     (__attribute__((address_space(3))) void*)l, 16, 0, 0);
}

// ---------------------------------------------------------------------------
// device-scope grid barrier (256 blocks, all co-resident: 1 block/CU).
// Slots live in ws, zeroed by prep_w each launch (ws is re-poisoned to 0xAA).
// ---------------------------------------------------------------------------
__device__ __forceinline__ void grid_barrier(unsigned* bar, int slot) {
    __syncthreads();
    if (threadIdx.x == 0) {
        __threadfence();  // release: drain this block's writes to device scope
        unsigned* p = bar + slot;
        __hip_atomic_fetch_add(p, 1u, __ATOMIC_RELEASE, __HIP_MEMORY_SCOPE_AGENT);
        while (__hip_atomic_load(p, __ATOMIC_ACQUIRE, __HIP_MEMORY_SCOPE_AGENT) < 256u)
            __builtin_amdgcn_s_sleep(2);
        __threadfence();  // acquire: invalidate stale L1/L2
    }
    __syncthreads();
}

// ---------------------------------------------------------------------------
// prep: w_s = kernel * (1/32)  [= 32 * (kernel/1024)], transposed copy, and
// zero the grid-barrier slots.
// ---------------------------------------------------------------------------
__global__ __launch_bounds__(256) void prep_w(const float* __restrict__ K,
                                              _Float16* __restrict__ w0,
                                              _Float16* __restrict__ w0T,
                                              unsigned* __restrict__ bar) {
    __shared__ float tile[64][65];
    const int t  = threadIdx.x;
    if (blockIdx.x == 0 && blockIdx.y == 0 && t < 64) bar[t] = 0u;
    const int bi = blockIdx.y * 64;
    const int bj = blockIdx.x * 64;
    const int r0 = t >> 4;
    const int c4 = (t & 15) * 4;
#pragma unroll
    for (int rr = 0; rr < 4; ++rr) {
        int r = r0 + rr * 16;
        f32x4 v = *(const f32x4*)&K[(size_t)(bi + r) * 1024 + bj + c4];
        v *= 0.03125f;
        half4v h;
        h[0] = (_Float16)v[0]; h[1] = (_Float16)v[1];
        h[2] = (_Float16)v[2]; h[3] = (_Float16)v[3];
        *(half4v*)&w0[(size_t)(bi + r) * 1024 + bj + c4] = h;
        tile[r][c4 + 0] = v[0]; tile[r][c4 + 1] = v[1];
        tile[r][c4 + 2] = v[2]; tile[r][c4 + 3] = v[3];
    }
    __syncthreads();
    const int cT = t >> 4;
    const int rT = (t & 15) * 4;
#pragma unroll
    for (int cc = 0; cc < 4; ++cc) {
        int c = cT + cc * 16;
        half4v h;
        h[0] = (_Float16)tile[rT + 0][c]; h[1] = (_Float16)tile[rT + 1][c];
        h[2] = (_Float16)tile[rT + 2][c]; h[3] = (_Float16)tile[rT + 3][c];
        *(half4v*)&w0T[(size_t)(bj + c) * 1024 + bi + rT] = h;
    }
}

// ---------------------------------------------------------------------------
// one 64x64-tile GEMM phase of the persistent kernel.
// C[m][n] = sum_k A[m][k] * BT[n][k], K=1024, BK=128 (8 iters), LDS dbuf.
// EPI==0: out = (fp16)acc                  (S_s = w_s^T w_s)
// EPI==1: w' = 1.5*wcur - (0.5/1024)*acc   (+ transposed copy)
// ---------------------------------------------------------------------------
template <int EPI>
__device__ __forceinline__ void gemm_phase(const _Float16* __restrict__ A,
                                           const _Float16* __restrict__ BT,
                                           const _Float16* __restrict__ wcur,
                                           _Float16* __restrict__ out,
                                           _Float16* __restrict__ outT,
                                           _Float16 (*sA)[8192], _Float16 (*sB)[8192],
                                           int m0, int n0, int t) {
    const int ln  = t & 63, wv = t >> 6;
    const int wm  = wv >> 1, wn = wv & 1;
    const int q   = ln >> 4, l15 = ln & 15;

    f32x4 acc[2][2];
#pragma unroll
    for (int i = 0; i < 2; ++i)
#pragma unroll
        for (int j = 0; j < 2; ++j) {
            acc[i][j][0] = 0.f; acc[i][j][1] = 0.f;
            acc[i][j][2] = 0.f; acc[i][j][3] = 0.f;
        }

    auto stage = [&](int buf, int k0) {
#pragma unroll
        for (int rnd = 0; rnd < 4; ++rnd) {
            int c = t + rnd * 256;          // granule 0..1023 (16 per row)
            int row = c >> 4, g = c & 15;
            int gs = g ^ (row & 15);        // XOR swizzle
            async_copy16(A + (size_t)(m0 + row) * 1024 + k0 + gs * 8, &sA[buf][c * 8]);
            async_copy16(BT + (size_t)(n0 + row) * 1024 + k0 + gs * 8, &sB[buf][c * 8]);
        }
    };
    auto frag = [&](const _Float16* s, int row, int kc) -> half8 {
        return *(const half8*)&s[row * 128 + ((kc ^ (row & 15)) << 3)];
    };

    stage(0, 0);
    int cur = 0;
#pragma unroll 1
    for (int it = 0; it < 8; ++it) {
        __syncthreads();
        if (it < 7) stage(cur ^ 1, (it + 1) * 128);
#pragma unroll
        for (int kk = 0; kk < 4; ++kk) {
            half8 a0 = frag(sA[cur], wm * 32 + 0  + l15, kk * 4 + q);
            half8 a1 = frag(sA[cur], wm * 32 + 16 + l15, kk * 4 + q);
            half8 b0 = frag(sB[cur], wn * 32 + 0  + l15, kk * 4 + q);
            half8 b1 = frag(sB[cur], wn * 32 + 16 + l15, kk * 4 + q);
            acc[0][0] = __builtin_amdgcn_mfma_f32_16x16x32_f16(a0, b0, acc[0][0], 0, 0, 0);
            acc[0][1] = __builtin_amdgcn_mfma_f32_16x16x32_f16(a0, b1, acc[0][1], 0, 0, 0);
            acc[1][0] = __builtin_amdgcn_mfma_f32_16x16x32_f16(a1, b0, acc[1][0], 0, 0, 0);
            acc[1][1] = __builtin_amdgcn_mfma_f32_16x16x32_f16(a1, b1, acc[1][1], 0, 0, 0);
        }
        cur ^= 1;
    }

#pragma unroll
    for (int im = 0; im < 2; ++im)
#pragma unroll
        for (int jn = 0; jn < 2; ++jn) {
            int row0 = m0 + wm * 32 + im * 16 + q * 4;
            int col  = n0 + wn * 32 + jn * 16 + l15;
            if (EPI == 0) {
#pragma unroll
                for (int r = 0; r < 4; ++r)
                    out[(size_t)(row0 + r) * 1024 + col] = (_Float16)acc[im][jn][r];
            } else {
                half4v hT;
#pragma unroll
                for (int r = 0; r < 4; ++r) {
                    float w0v = (float)wcur[(size_t)(row0 + r) * 1024 + col];
                    float nv  = 1.5f * w0v - 4.8828125e-4f * acc[im][jn][r];
                    _Float16 h = (_Float16)nv;
                    out[(size_t)(row0 + r) * 1024 + col] = h;
                    hT[r] = h;
                }
                *(half4v*)&outT[(size_t)col * 1024 + row0] = hT;
            }
        }
}

// ---------------------------------------------------------------------------
// persistent kernel: all 20 Bjorck iterations, 2 phases each, grid barriers.
// 256 blocks x 256 threads (1 block/CU, co-resident).
// ---------------------------------------------------------------------------
__global__ __launch_bounds__(256) void bjorck_iter(_Float16* __restrict__ wh0,
                                                   _Float16* __restrict__ wh1,
                                                   _Float16* __restrict__ wT0,
                                                   _Float16* __restrict__ wT1,
                                                   _Float16* __restrict__ Sh,
                                                   unsigned* __restrict__ bar) {
    __shared__ _Float16 sA[2][8192];   // 64 rows x 128 halves, dbuf (32 KB)
    __shared__ _Float16 sB[2][8192];
    const int t  = threadIdx.x;
    const int m0 = (blockIdx.x >> 4) * 64;
    const int n0 = (blockIdx.x & 15) * 64;
    _Float16* whp[2] = {wh0, wh1};
    _Float16* wTp[2] = {wT0, wT1};

#pragma unroll 1
    for (int it = 0; it < 20; ++it) {
        int c = it & 1, n = c ^ 1;
        // S_s = w_s^T w_s  (A = BT = wT rows, k contiguous)
        gemm_phase<0>(wTp[c], wTp[c], nullptr, Sh, nullptr, sA, sB, m0, n0, t);
        grid_barrier(bar, 2 * it);
        // w' = 1.5 w - (0.5/1024) w * S   (BT = S, symmetric)
        gemm_phase<1>(whp[c], Sh, whp[c], whp[n], wTp[n], sA, sB, m0, n0, t);
        if (it < 19) grid_barrier(bar, 2 * it + 1);
    }
}

// ---------------------------------------------------------------------------
// X f32 -> f16 one-shot conversion (pure BW pass).
// ---------------------------------------------------------------------------
__global__ __launch_bounds__(256) void xcvt(const float* __restrict__ X,
                                            _Float16* __restrict__ Xh) {
    size_t i = ((size_t)blockIdx.x * 256 + threadIdx.x) * 8;
    f32x4 v0 = *(const f32x4*)&X[i];
    f32x4 v1 = *(const f32x4*)&X[i + 4];
    half8 h;
    h[0] = (_Float16)v0[0]; h[1] = (_Float16)v0[1];
    h[2] = (_Float16)v0[2]; h[3] = (_Float16)v0[3];
    h[4] = (_Float16)v1[0]; h[5] = (_Float16)v1[1];
    h[6] = (_Float16)v1[2]; h[7] = (_Float16)v1[3];
    *(half8*)&Xh[i] = h;
}

// ---------------------------------------------------------------------------
// big GEMM v2 (fp16 A): m97 structure. Y = (1/32) * Xh * w_s + bias
// 128x128 tile, BK=32 (32 iters), both tiles via glds, XOR swizzle.
// ---------------------------------------------------------------------------
__global__ __launch_bounds__(256) void gemm_big2(const _Float16* __restrict__ Xh,
                                                 const _Float16* __restrict__ BT,
                                                 const float* __restrict__ bias,
                                                 float* __restrict__ Y) {
    __shared__ _Float16 sA[2][4096];   // 128 rows x 32 halves (8 KB)
    __shared__ _Float16 sB[2][4096];
    const int t  = threadIdx.x;
    const int m0 = blockIdx.y * 128, n0 = blockIdx.x * 128;
    const int ln = t & 63, wv = t >> 6;
    const int wm = wv >> 1, wn = wv & 1;
    const int q  = ln >> 4, l15 = ln & 15;

    f32x4 acc[4][4];
#pragma unroll
    for (int i = 0; i < 4; ++i)
#pragma unroll
        for (int j = 0; j < 4; ++j) {
            acc[i][j][0] = 0.f; acc[i][j][1] = 0.f;
            acc[i][j][2] = 0.f; acc[i][j][3] = 0.f;
        }

    auto stage = [&](int buf, int k0) {
#pragma unroll
        for (int rnd = 0; rnd < 2; ++rnd) {
            int c = t + rnd * 256;          // granule 0..511 (4 per row)
            int row = c >> 2, g = c & 3;
            int gs = g ^ (row & 3);
            async_copy16(Xh + (size_t)(m0 + row) * 1024 + k0 + gs * 8, &sA[buf][c * 8]);
            async_copy16(BT + (size_t)(n0 + row) * 1024 + k0 + gs * 8, &sB[buf][c * 8]);
        }
    };

    stage(0, 0);
    int cur = 0;
#pragma unroll 1
    for (int it = 0; it < 32; ++it) {
        __syncthreads();
        if (it < 31) stage(cur ^ 1, (it + 1) * 32);
        half8 a[4], b[4];
#pragma unroll
        for (int im = 0; im < 4; ++im) {
            int row = wm * 64 + im * 16 + l15;
            a[im] = *(const half8*)&sA[cur][row * 32 + ((q ^ (row & 3)) << 3)];
        }
#pragma unroll
        for (int jn = 0; jn < 4; ++jn) {
            int row = wn * 64 + jn * 16 + l15;
            b[jn] = *(const half8*)&sB[cur][row * 32 + ((q ^ (row & 3)) << 3)];
        }
#pragma unroll
        for (int im = 0; im < 4; ++im)
#pragma unroll
            for (int jn = 0; jn < 4; ++jn)
                acc[im][jn] = __builtin_amdgcn_mfma_f32_16x16x32_f16(a[im], b[jn], acc[im][jn], 0, 0, 0);
        cur ^= 1;
    }

#pragma unroll
    for (int jn = 0; jn < 4; ++jn) {
        int col = n0 + wn * 64 + jn * 16 + l15;
        float bv = bias[col];
#pragma unroll
        for (int im = 0; im < 4; ++im) {
            int row0 = m0 + wm * 64 + im * 16 + q * 4;
#pragma unroll
            for (int r = 0; r < 4; ++r)
                Y[(size_t)(row0 + r) * 1024 + col] = acc[im][jn][r] * 0.03125f + bv;
        }
    }
}

// ---------------------------------------------------------------------------
// big GEMM v1 (fallback if ws too small for Xh): inline f32->f16 staging.
// ---------------------------------------------------------------------------
__global__ __launch_bounds__(256) void gemm_big(const float* __restrict__ X,
                                                const _Float16* __restrict__ BT,
                                                const float* __restrict__ bias,
                                                float* __restrict__ Y) {
    __shared__ _Float16 sA[2][128 * 40];
    __shared__ _Float16 sB[2][128 * 32];
    const int t  = threadIdx.x;
    const int m0 = blockIdx.y * 128, n0 = blockIdx.x * 128;
    const int ln = t & 63, wv = t >> 6;
    const int wm = wv >> 1, wn = wv & 1;
    const int q  = ln >> 4, l15 = ln & 15;

    f32x4 acc[4][4];
#pragma unroll
    for (int i = 0; i < 4; ++i)
#pragma unroll
        for (int j = 0; j < 4; ++j) {
            acc[i][j][0] = 0.f; acc[i][j][1] = 0.f;
            acc[i][j][2] = 0.f; acc[i][j][3] = 0.f;
        }

    auto loadA = [&](int k0, f32x4* va) {
#pragma unroll
        for (int rnd = 0; rnd < 4; ++rnd) {
            int c = t + rnd * 256;
            int row = c >> 3, s4 = c & 7;
            va[rnd] = *(const f32x4*)&X[(size_t)(m0 + row) * 1024 + k0 + s4 * 4];
        }
    };
    auto writeA = [&](int buf, const f32x4* va) {
#pragma unroll
        for (int rnd = 0; rnd < 4; ++rnd) {
            int c = t + rnd * 256;
            int row = c >> 3, s4 = c & 7;
            half4v h;
            h[0] = (_Float16)va[rnd][0]; h[1] = (_Float16)va[rnd][1];
            h[2] = (_Float16)va[rnd][2]; h[3] = (_Float16)va[rnd][3];
            *(half4v*)&sA[buf][row * 40 + s4 * 4] = h;
        }
    };
    auto stageB = [&](int buf, int k0) {
#pragma unroll
        for (int rnd = 0; rnd < 2; ++rnd) {
            int c = t + rnd * 256;
            int row = c >> 2, s = c & 3;
            int gs = s ^ ((row >> 1) & 3);
            async_copy16(BT + (size_t)(n0 + row) * 1024 + k0 + gs * 8, &sB[buf][c * 8]);
        }
    };

    f32x4 va[4];
    loadA(0, va);
    stageB(0, 0);
    writeA(0, va);
    int cur = 0;
#pragma unroll 1
    for (int it = 0; it < 32; ++it) {
        __syncthreads();
        if (it < 31) {
            loadA((it + 1) * 32, va);
            stageB(cur ^ 1, (it + 1) * 32);
        }
        half8 a[4], b[4];
#pragma unroll
        for (int im = 0; im < 4; ++im) {
            int row = wm * 64 + im * 16 + l15;
            a[im] = *(const half8*)&sA[cur][row * 40 + q * 8];
        }
#pragma unroll
        for (int jn = 0; jn < 4; ++jn) {
            int row = wn * 64 + jn * 16 + l15;
            b[jn] = *(const half8*)&sB[cur][row * 32 + ((q ^ ((row >> 1) & 3)) << 3)];
        }
#pragma unroll
        for (int im = 0; im < 4; ++im)
#pragma unroll
            for (int jn = 0; jn < 4; ++jn)
                acc[im][jn] = __builtin_amdgcn_mfma_f32_16x16x32_f16(a[im], b[jn], acc[im][jn], 0, 0, 0);
        if (it < 31) writeA(cur ^ 1, va);
        cur ^= 1;
    }

#pragma unroll
    for (int jn = 0; jn < 4; ++jn) {
        int col = n0 + wn * 64 + jn * 16 + l15;
        float bv = bias[col];
#pragma unroll
        for (int im = 0; im < 4; ++im) {
            int row0 = m0 + wm * 64 + im * 16 + q * 4;
#pragma unroll
            for (int r = 0; r < 4; ++r)
                Y[(size_t)(row0 + r) * 1024 + col] = acc[im][jn][r] * 0.03125f + bv;
        }
    }
}

// ---------------------------------------------------------------------------
extern "C" void kernel_launch(void* const* d_in, const int* in_sizes, int n_in,
                              void* d_out, int out_size, void* d_ws, size_t ws_size,
                              hipStream_t stream) {
    (void)in_sizes; (void)n_in; (void)out_size;
    const float* x    = (const float*)d_in[0];
    const float* kern = (const float*)d_in[1];
    const float* bias = (const float*)d_in[2];
    float* y = (float*)d_out;

    char* ws = (char*)d_ws;
    const size_t SZ = (size_t)1024 * 1024 * sizeof(_Float16);  // 2 MB
    _Float16* wh[2] = {(_Float16*)(ws + 0 * SZ), (_Float16*)(ws + 1 * SZ)};
    _Float16* wT[2] = {(_Float16*)(ws + 2 * SZ), (_Float16*)(ws + 3 * SZ)};
    _Float16* Sh    = (_Float16*)(ws + 4 * SZ);
    unsigned* bar   = (unsigned*)(ws + 5 * SZ);
    _Float16* Xh    = (_Float16*)(ws + 5 * SZ + 4096);
    const size_t XH_BYTES = (size_t)32768 * 1024 * 2;  // 64 MiB
    const bool have_xh = ws_size >= 5 * SZ + 4096 + XH_BYTES;

    prep_w<<<dim3(16, 16), 256, 0, stream>>>(kern, wh[0], wT[0], bar);
    bjorck_iter<<<256, 256, 0, stream>>>(wh[0], wh[1], wT[0], wT[1], Sh, bar);
    // 20 iterations end with parity in slot 0 (wT[0])
    if (have_xh) {
        xcvt<<<16384, 256, 0, stream>>>(x, Xh);
        gemm_big2<<<dim3(8, 256), 256, 0, stream>>>(Xh, wT[0], bias, y);
    } else {
        gemm_big<<<dim3(8, 256), 256, 0, stream>>>(x, wT[0], bias, y);
    }
}

// Round 3
// 742.962 us; speedup vs baseline: 2.5812x; 2.5812x over previous
//
#include <hip/hip_runtime.h>
#include <cstdint>

typedef _Float16 half8 __attribute__((ext_vector_type(8)));
typedef _Float16 half4v __attribute__((ext_vector_type(4)));
typedef float f32x4 __attribute__((ext_vector_type(4)));

__device__ __forceinline__ void async_copy16(const void* g, void* l) {
    __builtin_amdgcn_global_load_lds((const __attribute__((address_space(1))) void*)g,
                                     (__attribute__((address_space(3))) void*)l, 16, 0, 0);
}

// ---------------------------------------------------------------------------
// prep: w_s = kernel * (1/32)   [= 32 * (kernel/1024)], plus transposed copy.
// ---------------------------------------------------------------------------
__global__ __launch_bounds__(256) void prep_w(const float* __restrict__ K,
                                              _Float16* __restrict__ w0,
                                              _Float16* __restrict__ w0T) {
    __shared__ float tile[64][65];
    const int t  = threadIdx.x;
    const int bi = blockIdx.y * 64;
    const int bj = blockIdx.x * 64;
    const int r0 = t >> 4;
    const int c4 = (t & 15) * 4;
#pragma unroll
    for (int rr = 0; rr < 4; ++rr) {
        int r = r0 + rr * 16;
        f32x4 v = *(const f32x4*)&K[(size_t)(bi + r) * 1024 + bj + c4];
        v *= 0.03125f;
        half4v h;
        h[0] = (_Float16)v[0]; h[1] = (_Float16)v[1];
        h[2] = (_Float16)v[2]; h[3] = (_Float16)v[3];
        *(half4v*)&w0[(size_t)(bi + r) * 1024 + bj + c4] = h;
        tile[r][c4 + 0] = v[0]; tile[r][c4 + 1] = v[1];
        tile[r][c4 + 2] = v[2]; tile[r][c4 + 3] = v[3];
    }
    __syncthreads();
    const int cT = t >> 4;
    const int rT = (t & 15) * 4;
#pragma unroll
    for (int cc = 0; cc < 4; ++cc) {
        int c = cT + cc * 16;
        half4v h;
        h[0] = (_Float16)tile[rT + 0][c]; h[1] = (_Float16)tile[rT + 1][c];
        h[2] = (_Float16)tile[rT + 2][c]; h[3] = (_Float16)tile[rT + 3][c];
        *(half4v*)&w0T[(size_t)(bj + c) * 1024 + bi + rT] = h;
    }
}

// ---------------------------------------------------------------------------
// small 1024x1024x1024 GEMM:  C[m][n] = sum_k A[m][k] * BT[n][k]
// EPI==0: out = (fp16)acc                  (S_s = w_s^T w_s, via A=BT=wT)
// EPI==1: w' = 1.5*wcur - (0.5/1024)*acc   (+ transposed copy)
// v2: 64x64 tile, 512 threads (8 waves = 2/SIMD: 4m x 2n, 1x2 frags each),
// BK=128 (8 iters), LDS dbuf 64 KB, glds staging, XOR swizzle,
// XCD-patch block swizzle (each XCD reads an 8m x 4n patch: 1.5 MB).
// ---------------------------------------------------------------------------
template <int EPI>
__global__ __launch_bounds__(512) void gemm1k(const _Float16* __restrict__ A,
                                              const _Float16* __restrict__ BT,
                                              const _Float16* __restrict__ wcur,
                                              _Float16* __restrict__ out,
                                              _Float16* __restrict__ outT) {
    __shared__ _Float16 sA[2][8192];   // 64 rows x 128 halves
    __shared__ _Float16 sB[2][8192];
    const int t = threadIdx.x;
    const int b = blockIdx.x;
    const int xcd = b & 7, j = b >> 3;
    const int m0 = (((xcd & 1) << 3) + (j & 7)) << 6;   // 16 m-tiles
    const int n0 = (((xcd >> 1) << 2) + (j >> 3)) << 6; // 16 n-tiles
    const int ln = t & 63, wv = t >> 6;
    const int wm = wv >> 1, wn = wv & 1;     // 4 x 2 waves
    const int q  = ln >> 4, l15 = ln & 15;

    f32x4 acc[2];
#pragma unroll
    for (int jn = 0; jn < 2; ++jn) {
        acc[jn][0] = 0.f; acc[jn][1] = 0.f;
        acc[jn][2] = 0.f; acc[jn][3] = 0.f;
    }

    auto stage = [&](int buf, int k0) {
#pragma unroll
        for (int rnd = 0; rnd < 2; ++rnd) {
            int c = t + rnd * 512;          // granule 0..1023 (16 per row)
            int row = c >> 4, g = c & 15;
            int gs = g ^ (row & 15);        // XOR swizzle
            async_copy16(A + (size_t)(m0 + row) * 1024 + k0 + gs * 8, &sA[buf][c * 8]);
            async_copy16(BT + (size_t)(n0 + row) * 1024 + k0 + gs * 8, &sB[buf][c * 8]);
        }
    };
    auto frag = [&](const _Float16* s, int row, int kc) -> half8 {
        return *(const half8*)&s[row * 128 + ((kc ^ (row & 15)) << 3)];
    };

    stage(0, 0);
    int cur = 0;
#pragma unroll 1
    for (int it = 0; it < 8; ++it) {
        __syncthreads();
        if (it < 7) stage(cur ^ 1, (it + 1) * 128);
#pragma unroll
        for (int kk = 0; kk < 4; ++kk) {
            half8 a0 = frag(sA[cur], wm * 16 + l15, kk * 4 + q);
            half8 b0 = frag(sB[cur], wn * 32 + 0  + l15, kk * 4 + q);
            half8 b1 = frag(sB[cur], wn * 32 + 16 + l15, kk * 4 + q);
            acc[0] = __builtin_amdgcn_mfma_f32_16x16x32_f16(a0, b0, acc[0], 0, 0, 0);
            acc[1] = __builtin_amdgcn_mfma_f32_16x16x32_f16(a0, b1, acc[1], 0, 0, 0);
        }
        cur ^= 1;
    }

    const int row0 = m0 + wm * 16 + q * 4;
#pragma unroll
    for (int jn = 0; jn < 2; ++jn) {
        int col = n0 + wn * 32 + jn * 16 + l15;
        if (EPI == 0) {
#pragma unroll
            for (int r = 0; r < 4; ++r)
                out[(size_t)(row0 + r) * 1024 + col] = (_Float16)acc[jn][r];
        } else {
            half4v hT;
#pragma unroll
            for (int r = 0; r < 4; ++r) {
                float w0v = (float)wcur[(size_t)(row0 + r) * 1024 + col];
                float nv  = 1.5f * w0v - 4.8828125e-4f * acc[jn][r];
                _Float16 h = (_Float16)nv;
                out[(size_t)(row0 + r) * 1024 + col] = h;
                hT[r] = h;
            }
            *(half4v*)&outT[(size_t)col * 1024 + row0] = hT;
        }
    }
}

// ---------------------------------------------------------------------------
// big GEMM: Y[32768][1024] = (1/32) * X(f32, cvt->f16) * w_s  + bias
// 128x128 tile, BK=32, 4 waves (2x2, each 64x64 = 4x4 frags), dbuf.
// A staged via VGPR (fp32 load -> cvt -> ds_write, padded rows), B via glds.
// v3: grid dim3(256,8) m-major so XCD = m-tile % 8 -> X fetched once chip-wide.
// ---------------------------------------------------------------------------
__global__ __launch_bounds__(256) void gemm_big(const float* __restrict__ X,
                                                const _Float16* __restrict__ BT,
                                                const float* __restrict__ bias,
                                                float* __restrict__ Y) {
    __shared__ _Float16 sA[2][128 * 40];   // pad: 40 halves/row
    __shared__ _Float16 sB[2][128 * 32];
    const int t  = threadIdx.x;
    const int m0 = blockIdx.x * 128, n0 = blockIdx.y * 128;  // m-major grid
    const int ln = t & 63, wv = t >> 6;
    const int wm = wv >> 1, wn = wv & 1;
    const int q  = ln >> 4, l15 = ln & 15;

    f32x4 acc[4][4];
#pragma unroll
    for (int i = 0; i < 4; ++i)
#pragma unroll
        for (int j = 0; j < 4; ++j) {
            acc[i][j][0] = 0.f; acc[i][j][1] = 0.f;
            acc[i][j][2] = 0.f; acc[i][j][3] = 0.f;
        }

    auto loadA = [&](int k0, f32x4* va) {
#pragma unroll
        for (int rnd = 0; rnd < 4; ++rnd) {
            int c = t + rnd * 256;          // 0..1023 float4-chunks (8/row)
            int row = c >> 3, s4 = c & 7;
            va[rnd] = *(const f32x4*)&X[(size_t)(m0 + row) * 1024 + k0 + s4 * 4];
        }
    };
    auto writeA = [&](int buf, const f32x4* va) {
#pragma unroll
        for (int rnd = 0; rnd < 4; ++rnd) {
            int c = t + rnd * 256;
            int row = c >> 3, s4 = c & 7;
            half4v h;
            h[0] = (_Float16)va[rnd][0]; h[1] = (_Float16)va[rnd][1];
            h[2] = (_Float16)va[rnd][2]; h[3] = (_Float16)va[rnd][3];
            *(half4v*)&sA[buf][row * 40 + s4 * 4] = h;
        }
    };
    auto stageB = [&](int buf, int k0) {
#pragma unroll
        for (int rnd = 0; rnd < 2; ++rnd) {
            int c = t + rnd * 256;          // 0..511 (4 chunks/row)
            int row = c >> 2, s = c & 3;
            int gs = s ^ ((row >> 1) & 3);
            async_copy16(BT + (size_t)(n0 + row) * 1024 + k0 + gs * 8, &sB[buf][c * 8]);
        }
    };

    f32x4 va[4];
    loadA(0, va);
    stageB(0, 0);
    writeA(0, va);
    int cur = 0;
#pragma unroll 1
    for (int it = 0; it < 32; ++it) {
        __syncthreads();
        if (it < 31) {
            loadA((it + 1) * 32, va);       // issue early; consumed after compute
            stageB(cur ^ 1, (it + 1) * 32);
        }
        half8 a[4], b[4];
#pragma unroll
        for (int im = 0; im < 4; ++im) {
            int row = wm * 64 + im * 16 + l15;
            a[im] = *(const half8*)&sA[cur][row * 40 + q * 8];
        }
#pragma unroll
        for (int jn = 0; jn < 4; ++jn) {
            int row = wn * 64 + jn * 16 + l15;
            b[jn] = *(const half8*)&sB[cur][row * 32 + ((q ^ ((row >> 1) & 3)) << 3)];
        }
#pragma unroll
        for (int im = 0; im < 4; ++im)
#pragma unroll
            for (int jn = 0; jn < 4; ++jn)
                acc[im][jn] = __builtin_amdgcn_mfma_f32_16x16x32_f16(a[im], b[jn], acc[im][jn], 0, 0, 0);
        if (it < 31) writeA(cur ^ 1, va);
        cur ^= 1;
    }

#pragma unroll
    for (int jn = 0; jn < 4; ++jn) {
        int col = n0 + wn * 64 + jn * 16 + l15;
        float bv = bias[col];
#pragma unroll
        for (int im = 0; im < 4; ++im) {
            int row0 = m0 + wm * 64 + im * 16 + q * 4;
#pragma unroll
            for (int r = 0; r < 4; ++r)
                Y[(size_t)(row0 + r) * 1024 + col] = acc[im][jn][r] * 0.03125f + bv;
        }
    }
}

// ---------------------------------------------------------------------------
extern "C" void kernel_launch(void* const* d_in, const int* in_sizes, int n_in,
                              void* d_out, int out_size, void* d_ws, size_t ws_size,
                              hipStream_t stream) {
    (void)in_sizes; (void)n_in; (void)out_size; (void)ws_size;
    const float* x    = (const float*)d_in[0];
    const float* kern = (const float*)d_in[1];
    const float* bias = (const float*)d_in[2];
    float* y = (float*)d_out;

    char* ws = (char*)d_ws;
    const size_t SZ = (size_t)1024 * 1024 * sizeof(_Float16);  // 2 MB
    _Float16* wh[2] = {(_Float16*)(ws + 0 * SZ), (_Float16*)(ws + 1 * SZ)};
    _Float16* wT[2] = {(_Float16*)(ws + 2 * SZ), (_Float16*)(ws + 3 * SZ)};
    _Float16* Sh    = (_Float16*)(ws + 4 * SZ);

    prep_w<<<dim3(16, 16), 256, 0, stream>>>(kern, wh[0], wT[0]);

    for (int it = 0; it < 20; ++it) {
        int c = it & 1, n = c ^ 1;
        // S_s = w_s^T w_s : A = BT = wT (both row-slabs of w^T, k contiguous)
        gemm1k<0><<<256, 512, 0, stream>>>(wT[c], wT[c], nullptr, Sh, nullptr);
        // w_next = 1.5 w - (0.5/1024) * (w_s * S_s); BT = S (symmetric)
        gemm1k<1><<<256, 512, 0, stream>>>(wh[c], Sh, wh[c], wh[n], wT[n]);
    }
    // final: y = (1/32) x * w_s + bias ; BT = wT (final parity lands in slot 0)
    gemm_big<<<dim3(256, 8), 256, 0, stream>>>(x, wT[0], bias, y);
}